// Round 1
// baseline (229.243 us; speedup 1.0000x reference)
//
#include <hip/hip_runtime.h>
#include <cstdint>
#include <cstddef>

// Problem sizes (fixed by the reference)
#define MDIM 16384   // N_INPUT
#define CDIM 4096    // NUM_CENTERS
#define DDIM 256     // DIM
#define KDIM 512     // folded K = 2*DIM

typedef __bf16 bf16x8 __attribute__((ext_vector_type(8)));
typedef float  f32x4  __attribute__((ext_vector_type(4)));

// ---------------------------------------------------------------------------
// prep_a: A'[n][d]     = x[n][d]          (cross-term slot)
//         A'[n][256+d] = x[n][d]^2        (x^2 term slot)
// also zeroes score[0..MDIM)
// ---------------------------------------------------------------------------
__global__ void prep_a(const float* __restrict__ x,
                       __bf16* __restrict__ Ap,
                       float* __restrict__ score) {
    int idx = blockIdx.x * 256 + threadIdx.x;   // over MDIM*DDIM
    int n = idx >> 8;
    int d = idx & 255;
    float v = x[idx];
    Ap[(size_t)n * KDIM + d]        = (__bf16)v;
    Ap[(size_t)n * KDIM + DDIM + d] = (__bf16)(v * v);
    if (idx < MDIM) score[idx] = 0.0f;
}

// ---------------------------------------------------------------------------
// prep_b: inv = 1/(2 s^2)
//         B'[c][d]     = -2 * centers * inv
//         B'[c][256+d] = inv
//         constc[c]    = sum_d centers^2 * inv   (fp32)
// one block (256 threads) per center c
// ---------------------------------------------------------------------------
__global__ void prep_b(const float* __restrict__ centers,
                       const float* __restrict__ sigmas,
                       __bf16* __restrict__ Bp,
                       float* __restrict__ constc) {
    int c = blockIdx.x;
    int d = threadIdx.x;           // 0..255
    float cv  = centers[c * DDIM + d];
    float s   = sigmas[c * DDIM + d];
    float inv = 1.0f / (2.0f * s * s);
    Bp[(size_t)c * KDIM + d]        = (__bf16)(-2.0f * cv * inv);
    Bp[(size_t)c * KDIM + DDIM + d] = (__bf16)inv;

    float t = cv * cv * inv;
    __shared__ float red[4];
    for (int m = 32; m; m >>= 1) t += __shfl_down(t, m, 64);
    if ((threadIdx.x & 63) == 0) red[threadIdx.x >> 6] = t;
    __syncthreads();
    if (threadIdx.x == 0) constc[c] = red[0] + red[1] + red[2] + red[3];
}

// ---------------------------------------------------------------------------
// Fused GEMM + exp + weighted C-reduction.
// d2 = A' B'^T + constc ; score[m] += sum_n exp(-d2[m][n]) * w[n]
// 128x128 tile / block, BK=64, 4 waves, 4x4 16x16x32 MFMA subtiles per wave.
// m97 structure: global_load_lds width=16, contiguous [row][64] LDS tiles.
// ---------------------------------------------------------------------------
__global__ __launch_bounds__(256) void gemm_fused(
    const __bf16* __restrict__ A, const __bf16* __restrict__ B,
    const float* __restrict__ constc, const float* __restrict__ w,
    float* __restrict__ score) {

    __shared__ __bf16 As[128 * 64];   // 16 KB
    __shared__ __bf16 Bs[128 * 64];   // 16 KB

    const int tid  = threadIdx.x;
    const int wave = tid >> 6;
    const int lane = tid & 63;
    const int quad = lane >> 4;      // 0..3
    const int l16  = lane & 15;

    const int bm = blockIdx.y;       // 0..127  (M blocks)
    const int bn = blockIdx.x;       // 0..31   (C blocks)

    const int wave_m = (wave & 1) * 64;
    const int wave_n = (wave >> 1) * 64;

    f32x4 acc[4][4] = {};

    // staging geometry: one global_load_lds(16B) per lane stages 1024 B
    // = 8 rows x 64 k(bf16). chunk = 8-row slab of the 128-row tile.
    const int st_row = lane >> 3;         // 0..7 within slab
    const int st_k   = (lane & 7) * 8;    // bf16 element offset in k

    const __bf16* Abase = A + (size_t)(bm * 128) * KDIM;
    const __bf16* Bbase = B + (size_t)(bn * 128) * KDIM;

    for (int k0 = 0; k0 < KDIM; k0 += 64) {
        #pragma unroll
        for (int c = 0; c < 4; ++c) {
            int chunk = wave * 4 + c;                 // 0..15
            const __bf16* ga = Abase + (size_t)(chunk * 8 + st_row) * KDIM + k0 + st_k;
            const __bf16* gb = Bbase + (size_t)(chunk * 8 + st_row) * KDIM + k0 + st_k;
            __builtin_amdgcn_global_load_lds(
                (const __attribute__((address_space(1))) void*)ga,
                (__attribute__((address_space(3))) void*)(As + chunk * 512), 16, 0, 0);
            __builtin_amdgcn_global_load_lds(
                (const __attribute__((address_space(1))) void*)gb,
                (__attribute__((address_space(3))) void*)(Bs + chunk * 512), 16, 0, 0);
        }
        __syncthreads();   // compiler drains vmcnt before s_barrier

        #pragma unroll
        for (int kk = 0; kk < 64; kk += 32) {
            bf16x8 af[4], bf[4];
            #pragma unroll
            for (int i = 0; i < 4; ++i)
                af[i] = *(const bf16x8*)(As + (wave_m + i * 16 + l16) * 64 + kk + quad * 8);
            #pragma unroll
            for (int j = 0; j < 4; ++j)
                bf[j] = *(const bf16x8*)(Bs + (wave_n + j * 16 + l16) * 64 + kk + quad * 8);
            #pragma unroll
            for (int i = 0; i < 4; ++i)
                #pragma unroll
                for (int j = 0; j < 4; ++j)
                    acc[i][j] = __builtin_amdgcn_mfma_f32_16x16x32_bf16(
                        af[i], bf[j], acc[i][j], 0, 0, 0);
        }
        __syncthreads();   // protect LDS for next stage
    }

    // Epilogue: d2 -> exp -> *w -> reduce over the 128 columns of this tile.
    // C/D layout (16x16x32): col = lane&15 (=n), row = quad*4 + reg (=m).
    const int n0 = bn * 128 + wave_n + l16;
    float rowsum[4][4];
    #pragma unroll
    for (int i = 0; i < 4; ++i)
        #pragma unroll
        for (int r = 0; r < 4; ++r) rowsum[i][r] = 0.0f;

    const float NEG_LOG2E = -1.4426950408889634f;
    #pragma unroll
    for (int j = 0; j < 4; ++j) {
        int ng = n0 + j * 16;
        float wj = w[ng];
        float cj = constc[ng];
        #pragma unroll
        for (int i = 0; i < 4; ++i)
            #pragma unroll
            for (int r = 0; r < 4; ++r) {
                float d2 = acc[i][j][r] + cj;
                rowsum[i][r] += exp2f(NEG_LOG2E * d2) * wj;
            }
    }

    // butterfly-reduce across the 16 lanes sharing the same rows
    #pragma unroll
    for (int mask = 1; mask < 16; mask <<= 1)
        #pragma unroll
        for (int i = 0; i < 4; ++i)
            #pragma unroll
            for (int r = 0; r < 4; ++r)
                rowsum[i][r] += __shfl_xor(rowsum[i][r], mask, 64);

    if (l16 == 0) {
        #pragma unroll
        for (int i = 0; i < 4; ++i)
            #pragma unroll
            for (int r = 0; r < 4; ++r) {
                int mg = bm * 128 + wave_m + i * 16 + quad * 4 + r;
                atomicAdd(&score[mg], rowsum[i][r]);
            }
    }
}

// ---------------------------------------------------------------------------
// finalize: out[n] = sigmoid(score[n] + b)
// ---------------------------------------------------------------------------
__global__ void finalize(const float* __restrict__ score,
                         const float* __restrict__ b,
                         float* __restrict__ out) {
    int n = blockIdx.x * 256 + threadIdx.x;
    if (n < MDIM) {
        float s = score[n] + b[0];
        out[n] = 1.0f / (1.0f + exp2f(-1.4426950408889634f * s));
    }
}

extern "C" void kernel_launch(void* const* d_in, const int* in_sizes, int n_in,
                              void* d_out, int out_size, void* d_ws, size_t ws_size,
                              hipStream_t stream) {
    const float* x       = (const float*)d_in[0];
    const float* centers = (const float*)d_in[1];
    const float* sigmas  = (const float*)d_in[2];
    const float* w_lin   = (const float*)d_in[3];
    const float* b_lin   = (const float*)d_in[4];
    float* out = (float*)d_out;

    char* ws = (char*)d_ws;
    __bf16* Ap    = (__bf16*)ws;                                   // 16 MB
    __bf16* Bp    = (__bf16*)(ws + (size_t)MDIM * KDIM * 2);       // 4 MB
    float*  cc    = (float*)(ws + (size_t)MDIM * KDIM * 2
                                + (size_t)CDIM * KDIM * 2);        // 16 KB
    float*  score = (float*)((char*)cc + CDIM * sizeof(float));    // 64 KB

    prep_a<<<dim3(MDIM * DDIM / 256), dim3(256), 0, stream>>>(x, Ap, score);
    prep_b<<<dim3(CDIM), dim3(256), 0, stream>>>(centers, sigmas, Bp, cc);
    gemm_fused<<<dim3(CDIM / 128, MDIM / 128), dim3(256), 0, stream>>>(
        Ap, Bp, cc, w_lin, score);
    finalize<<<dim3((MDIM + 255) / 256), dim3(256), 0, stream>>>(score, b_lin, out);
}

// Round 2
// 172.441 us; speedup vs baseline: 1.3294x; 1.3294x over previous
//
#include <hip/hip_runtime.h>
#include <cstdint>
#include <cstddef>

// Problem sizes (fixed by the reference)
#define MDIM 16384   // N_INPUT
#define CDIM 4096    // NUM_CENTERS
#define DDIM 256     // DIM
#define KDIM 512     // folded K = 2*DIM

typedef __bf16 bf16x8 __attribute__((ext_vector_type(8)));
typedef __bf16 bf16x4 __attribute__((ext_vector_type(4)));
typedef float  f32x4  __attribute__((ext_vector_type(4)));

// ---------------------------------------------------------------------------
// Fused prep:
//  blocks [0,4096):   A'[n][d] = x, A'[n][256+d] = x^2 ; zero score
//  blocks [4096,5120): inv = 1/(2 s^2); B'[c][d] = -2*c*inv; B'[c][256+d]=inv
//                      constc[c] = sum_d c^2*inv  (one wave per center)
// ---------------------------------------------------------------------------
__global__ __launch_bounds__(256) void prep(
    const float* __restrict__ x, const float* __restrict__ centers,
    const float* __restrict__ sigmas,
    __bf16* __restrict__ Ap, __bf16* __restrict__ Bp,
    float* __restrict__ constc, float* __restrict__ score) {
    int b = blockIdx.x;
    int tid = threadIdx.x;
    if (b < 4096) {
        int idx4 = b * 256 + tid;                 // over MDIM*DDIM/4
        float4 v = ((const float4*)x)[idx4];
        int n = idx4 >> 6, dq = idx4 & 63;
        bf16x4 a0 = { (__bf16)v.x, (__bf16)v.y, (__bf16)v.z, (__bf16)v.w };
        bf16x4 a1 = { (__bf16)(v.x * v.x), (__bf16)(v.y * v.y),
                      (__bf16)(v.z * v.z), (__bf16)(v.w * v.w) };
        *(bf16x4*)(Ap + (size_t)n * KDIM + dq * 4)        = a0;
        *(bf16x4*)(Ap + (size_t)n * KDIM + DDIM + dq * 4) = a1;
        if (idx4 < MDIM) score[idx4] = 0.0f;
    } else {
        int gid = (b - 4096) * 256 + tid;         // over CDIM*DDIM/4
        int c = gid >> 6, q = gid & 63;
        float4 cv = ((const float4*)centers)[gid];
        float4 sv = ((const float4*)sigmas)[gid];
        float ix = 1.0f / (2.0f * sv.x * sv.x);
        float iy = 1.0f / (2.0f * sv.y * sv.y);
        float iz = 1.0f / (2.0f * sv.z * sv.z);
        float iw = 1.0f / (2.0f * sv.w * sv.w);
        bf16x4 b0 = { (__bf16)(-2.0f * cv.x * ix), (__bf16)(-2.0f * cv.y * iy),
                      (__bf16)(-2.0f * cv.z * iz), (__bf16)(-2.0f * cv.w * iw) };
        bf16x4 b1 = { (__bf16)ix, (__bf16)iy, (__bf16)iz, (__bf16)iw };
        *(bf16x4*)(Bp + (size_t)c * KDIM + q * 4)        = b0;
        *(bf16x4*)(Bp + (size_t)c * KDIM + DDIM + q * 4) = b1;
        float t = cv.x * cv.x * ix + cv.y * cv.y * iy
                + cv.z * cv.z * iz + cv.w * cv.w * iw;
        #pragma unroll
        for (int m = 32; m; m >>= 1) t += __shfl_down(t, m, 64);
        if ((tid & 63) == 0) constc[c] = t;       // one wave == one center
    }
}

// ---------------------------------------------------------------------------
// Fused GEMM + exp + weighted C-reduction.
// d2 = A' B'^T + constc ; score[m] += sum_n exp(-d2[m][n]) * w[n]
// 128x128 tile, BK=64, 4 waves, 4x4 16x16x32 MFMA subtiles/wave.
// LDS layout XOR-swizzled: row r, global k-chunk g (8 bf16) lives at slot
// s = g ^ (r&7)  ->  fragment ds_read_b128 is 2-way-aliased (free, m136)
// instead of 16-way conflicted (5.7x).
// ---------------------------------------------------------------------------
__global__ __launch_bounds__(256, 4) void gemm_fused(
    const __bf16* __restrict__ A, const __bf16* __restrict__ B,
    const float* __restrict__ constc, const float* __restrict__ w,
    float* __restrict__ score) {

    __shared__ __bf16 As[128 * 64];   // 16 KB
    __shared__ __bf16 Bs[128 * 64];   // 16 KB

    const int tid  = threadIdx.x;
    const int wave = tid >> 6;
    const int lane = tid & 63;
    const int quad = lane >> 4;      // 0..3
    const int l16  = lane & 15;

    const int bm = blockIdx.y;       // 0..127  (M blocks)
    const int bn = blockIdx.x;       // 0..31   (C blocks)

    const int wave_m = (wave & 1) * 64;
    const int wave_n = (wave >> 1) * 64;

    f32x4 acc[4][4] = {};

    // staging: lane writes LDS at base + lane*16B = row (lane>>3), slot (lane&7).
    // To honor the swizzle, lane FETCHES global k-chunk (lane&7)^(lane>>3).
    const int st_row = lane >> 3;                    // 0..7
    const int st_k   = ((lane & 7) ^ st_row) * 8;    // swizzled global chunk

    const __bf16* Abase = A + (size_t)(bm * 128) * KDIM;
    const __bf16* Bbase = B + (size_t)(bn * 128) * KDIM;

    for (int k0 = 0; k0 < KDIM; k0 += 64) {
        #pragma unroll
        for (int c = 0; c < 4; ++c) {
            int chunk = wave * 4 + c;                 // 0..15 (8-row slab)
            const __bf16* ga = Abase + (size_t)(chunk * 8 + st_row) * KDIM + k0 + st_k;
            const __bf16* gb = Bbase + (size_t)(chunk * 8 + st_row) * KDIM + k0 + st_k;
            __builtin_amdgcn_global_load_lds(
                (const __attribute__((address_space(1))) void*)ga,
                (__attribute__((address_space(3))) void*)(As + chunk * 512), 16, 0, 0);
            __builtin_amdgcn_global_load_lds(
                (const __attribute__((address_space(1))) void*)gb,
                (__attribute__((address_space(3))) void*)(Bs + chunk * 512), 16, 0, 0);
        }
        __syncthreads();

        #pragma unroll
        for (int kk = 0; kk < 64; kk += 32) {
            const int kc = quad + (kk >> 3);          // global k-chunk this lane needs
            const int sl = (kc ^ (l16 & 7)) * 8;      // swizzled LDS slot (elems)
            bf16x8 af[4], bf[4];
            #pragma unroll
            for (int i = 0; i < 4; ++i)
                af[i] = *(const bf16x8*)(As + (wave_m + i * 16 + l16) * 64 + sl);
            #pragma unroll
            for (int j = 0; j < 4; ++j)
                bf[j] = *(const bf16x8*)(Bs + (wave_n + j * 16 + l16) * 64 + sl);
            #pragma unroll
            for (int i = 0; i < 4; ++i)
                #pragma unroll
                for (int j = 0; j < 4; ++j)
                    acc[i][j] = __builtin_amdgcn_mfma_f32_16x16x32_bf16(
                        af[i], bf[j], acc[i][j], 0, 0, 0);
        }
        __syncthreads();
    }

    // Epilogue: d2 -> exp -> *w -> reduce over this tile's 128 columns.
    // C/D layout (16x16x32): col = lane&15 (=n), row = quad*4 + reg (=m).
    const int n0 = bn * 128 + wave_n + l16;
    float rowsum[4][4];
    #pragma unroll
    for (int i = 0; i < 4; ++i)
        #pragma unroll
        for (int r = 0; r < 4; ++r) rowsum[i][r] = 0.0f;

    const float NEG_LOG2E = -1.4426950408889634f;
    #pragma unroll
    for (int j = 0; j < 4; ++j) {
        int ng = n0 + j * 16;
        float wj = w[ng];
        float cj = constc[ng];
        #pragma unroll
        for (int i = 0; i < 4; ++i)
            #pragma unroll
            for (int r = 0; r < 4; ++r) {
                float d2 = acc[i][j][r] + cj;
                rowsum[i][r] += exp2f(NEG_LOG2E * d2) * wj;
            }
    }

    #pragma unroll
    for (int mask = 1; mask < 16; mask <<= 1)
        #pragma unroll
        for (int i = 0; i < 4; ++i)
            #pragma unroll
            for (int r = 0; r < 4; ++r)
                rowsum[i][r] += __shfl_xor(rowsum[i][r], mask, 64);

    if (l16 == 0) {
        #pragma unroll
        for (int i = 0; i < 4; ++i)
            #pragma unroll
            for (int r = 0; r < 4; ++r) {
                int mg = bm * 128 + wave_m + i * 16 + quad * 4 + r;
                atomicAdd(&score[mg], rowsum[i][r]);
            }
    }
}

// ---------------------------------------------------------------------------
// finalize: out[n] = sigmoid(score[n] + b)
// ---------------------------------------------------------------------------
__global__ void finalize(const float* __restrict__ score,
                         const float* __restrict__ b,
                         float* __restrict__ out) {
    int n = blockIdx.x * 256 + threadIdx.x;
    if (n < MDIM) {
        float s = score[n] + b[0];
        out[n] = 1.0f / (1.0f + exp2f(-1.4426950408889634f * s));
    }
}

extern "C" void kernel_launch(void* const* d_in, const int* in_sizes, int n_in,
                              void* d_out, int out_size, void* d_ws, size_t ws_size,
                              hipStream_t stream) {
    const float* x       = (const float*)d_in[0];
    const float* centers = (const float*)d_in[1];
    const float* sigmas  = (const float*)d_in[2];
    const float* w_lin   = (const float*)d_in[3];
    const float* b_lin   = (const float*)d_in[4];
    float* out = (float*)d_out;

    char* ws = (char*)d_ws;
    __bf16* Ap    = (__bf16*)ws;                                   // 16 MB
    __bf16* Bp    = (__bf16*)(ws + (size_t)MDIM * KDIM * 2);       // 4 MB
    float*  cc    = (float*)(ws + (size_t)MDIM * KDIM * 2
                                + (size_t)CDIM * KDIM * 2);        // 16 KB
    float*  score = (float*)((char*)cc + CDIM * sizeof(float));    // 64 KB

    prep<<<dim3(4096 + 1024), dim3(256), 0, stream>>>(
        x, centers, sigmas, Ap, Bp, cc, score);
    gemm_fused<<<dim3(CDIM / 128, MDIM / 128), dim3(256), 0, stream>>>(
        Ap, Bp, cc, w_lin, score);
    finalize<<<dim3((MDIM + 255) / 256), dim3(256), 0, stream>>>(score, b_lin, out);
}